// Round 14
// baseline (149.329 us; speedup 1.0000x reference)
//
#include <hip/hip_runtime.h>

// DcorLoss: dcor(x, y) for x,y [8192,128] fp32 -> single scalar.
//
// <HaH,HbH> = sum(a_ij b_ij) - (2/n) sum_i ra_i rb_i + Sa Sb/n^2: one fused
// pass over 128x128 pair-tiles: bf16 gram (MFMA 16x16x32) -> distances ->
// f32 block-local scalar products + row/col sums, f64 per-tile spill.
// Upper triangle only; off-diag tiles doubled + transposed col-sums.
//
// R14: DIRECT-GLOBAL + SCHED_BARRIER-FENCED REGISTER PING-PONG. R13 failed
// because the compiler SANK the prefetch loads to their uses (VGPR=80
// proves both operand sets were never live) -> serial load->MFMA chains =
// R9. Fix: __builtin_amdgcn_sched_barrier(0) between every {6-load issue}
// group and {8-MFMA} group -- no instruction may cross, so chunk k+2's
// loads stay issued 2 MFMA phases early and the compiler's automatic
// vmcnt insertion produces counted waits. Register budget kept <=128:
// accY zero-init deferred past X phase; X distances bf16-packed (16 regs)
// before Y gram. Zero K-loop barriers; LDS = nl/rsum/pr only (4.6 KB).

typedef float f32x4 __attribute__((ext_vector_type(4)));
typedef __bf16 bf16x8 __attribute__((ext_vector_type(8)));
typedef __bf16 bf16x2 __attribute__((ext_vector_type(2)));

#define NR 8192
#define D 128
#define TILE 128
#define GB 64          /* NR / TILE */
#define NT 2080        /* GB*(GB+1)/2 */

// ---------------- workspace layout (bytes) ----------------
#define OFF_YB  2097152u
#define OFF_NX  4194304u
#define OFF_NY  (OFF_NX + 32768u)
#define OFF_RPX (OFF_NY + 32768u)               /* 64*64*128 f32 = 2 MB */
#define OFF_RPY (OFF_RPX + 2097152u)            /* 2 MB */
#define OFF_PP  (OFF_RPY + 2097152u)            /* 3*2080 f64 */
#define OFF_SB  (OFF_PP + 49920u)               /* 64*5 f64 */
#define WS_NEED (OFF_SB + 2560u)

#define SBAR() __builtin_amdgcn_sched_barrier(0)

__device__ __forceinline__ unsigned short bf16_rne(float f) {
    union { float f; unsigned u; } c; c.f = f;
    unsigned u = c.u;
    u += 0x7FFFu + ((u >> 16) & 1u);
    return (unsigned short)(u >> 16);
}

// One wave per row: fp32 -> bf16 (RNE), LINEAR layout + fp32 row sq-norm.
__global__ __launch_bounds__(256) void prep_kernel(
    const float* __restrict__ x, const float* __restrict__ y,
    unsigned short* __restrict__ xb, unsigned short* __restrict__ yb,
    float* __restrict__ nx, float* __restrict__ ny)
{
    int gid = blockIdx.x * 256 + threadIdx.x;
    int wave = gid >> 6;
    int lane = threadIdx.x & 63;
    const float* src; unsigned short* db; float* dn; int row;
    if (wave < NR) { src = x; db = xb; dn = nx; row = wave; }
    else           { src = y; db = yb; dn = ny; row = wave - NR; }

    const float2 v = *reinterpret_cast<const float2*>(src + (size_t)row * D + lane * 2);
    float s = v.x * v.x + v.y * v.y;
    unsigned packed = (unsigned)bf16_rne(v.x) | ((unsigned)bf16_rne(v.y) << 16);
    *reinterpret_cast<unsigned*>(db + (size_t)row * D + lane * 2) = packed;
#pragma unroll
    for (int m = 1; m < 64; m <<= 1) s += __shfl_xor(s, m);
    if (lane == 0) dn[row] = s;
}

// butterfly step S for a 16-value array reduced over the 16-lane lrow group
#define BSTEP(arr, S) {                                                    \
    const int b_ = (lrow >> (S)) & 1;                                      \
    _Pragma("unroll")                                                      \
    for (int i_ = 0; i_ < (8 >> (S)); ++i_) {                              \
        float k_ = b_ ? arr[2 * i_ + 1] : arr[2 * i_];                     \
        float s_ = b_ ? arr[2 * i_] : arr[2 * i_ + 1];                     \
        arr[i_] = k_ + __shfl_xor(s_, 1 << (S));                           \
    } }

// issue one K=32 chunk's operands (6 x global_load_dwordx4)
#define LOADOPS(da, db2, TiB, TjB, kk)                                     \
    {                                                                      \
        _Pragma("unroll")                                                  \
        for (int m_ = 0; m_ < 4; ++m_)                                     \
            da[m_] = *reinterpret_cast<const bf16x8*>((TiB) + aoff[m_] + (kk) * 64); \
        _Pragma("unroll")                                                  \
        for (int n_ = 0; n_ < 2; ++n_)                                     \
            db2[n_] = *reinterpret_cast<const bf16x8*>((TjB) + boff[n_] + (kk) * 64); \
    }

// 8 MFMAs on one operand set
#define MFMA8(da, db2, acc)                                                \
    {                                                                      \
        _Pragma("unroll")                                                  \
        for (int m_ = 0; m_ < 4; ++m_)                                     \
            _Pragma("unroll")                                              \
            for (int n_ = 0; n_ < 2; ++n_)                                 \
                acc[m_][n_] = __builtin_amdgcn_mfma_f32_16x16x32_bf16(     \
                    da[m_], db2[n_], acc[m_][n_], 0, 0, 0);                \
    }

// One 128x128 pair-tile per block, 8 waves (2 row x 4 col quadrants of
// 64x32), 4x2 frags of mfma_f32_16x16x32_bf16. Direct-global operands,
// sched_barrier-fenced 2-deep ping-pong, no K-loop barriers.
__global__ __launch_bounds__(512) void dcor_main12(
    const unsigned short* __restrict__ xb, const unsigned short* __restrict__ yb,
    const float* __restrict__ nx, const float* __restrict__ ny,
    float* __restrict__ RPx, float* __restrict__ RPy,
    double* __restrict__ Pp /* [3][NT] */)
{
    // XCD-chunked swizzle (8 XCDs, NT % 8 == 0 -> bijective)
    const int t = (blockIdx.x & 7) * (NT / 8) + (blockIdx.x >> 3);
    // triangular index t -> (bi, bj), bi <= bj
    double qd = 2.0 * GB + 1.0;
    int bi = (int)((qd - sqrt(qd * qd - 8.0 * (double)t)) * 0.5);
    while (bi > 0 && bi * GB - bi * (bi - 1) / 2 > t) --bi;
    while ((bi + 1) * GB - (bi + 1) * bi / 2 <= t) ++bi;
    const int bj = bi + (t - (bi * GB - bi * (bi - 1) / 2));
    const bool diag = (bi == bj);

    __shared__ float nl[4][TILE];   // 0:x rows 1:x cols 2:y rows 3:y cols
    __shared__ float rsum[4][TILE]; // x-row, y-row, x-col, y-col
    __shared__ float pr[3][8];

    const int tid  = threadIdx.x;
    const int lane = tid & 63, wid = tid >> 6;
    const int wr = wid >> 2, wc = wid & 3;        // 2x4 wave grid
    const int lrow = lane & 15, lkb = lane >> 4;

    if (tid < TILE) {
        nl[0][tid] = nx[bi * TILE + tid];
        nl[1][tid] = nx[bj * TILE + tid];
        nl[2][tid] = ny[bi * TILE + tid];
        nl[3][tid] = ny[bj * TILE + tid];
        rsum[0][tid] = 0.f; rsum[1][tid] = 0.f;
        rsum[2][tid] = 0.f; rsum[3][tid] = 0.f;
    }
    __syncthreads();                 // B1: nl/rsum visible (only K-side bar)

    // per-thread byte offsets within a panel (row * 256B + lkb * 16B)
    int aoff[4], boff[2];
#pragma unroll
    for (int m = 0; m < 4; ++m)
        aoff[m] = (wr * 64 + m * 16 + lrow) * 256 + lkb * 16;
#pragma unroll
    for (int nf = 0; nf < 2; ++nf)
        boff[nf] = (wc * 32 + nf * 16 + lrow) * 256 + lkb * 16;

    const char* TiX = (const char*)xb + (size_t)bi * TILE * 256;
    const char* TjX = (const char*)xb + (size_t)bj * TILE * 256;
    const char* TiY = (const char*)yb + (size_t)bi * TILE * 256;
    const char* TjY = (const char*)yb + (size_t)bj * TILE * 256;

    // C frag: row = (lane>>4)*4 + r, col = lane&15. Norms in regs; raw v_sqrt.
    auto to_dist = [&](f32x4 (&acc)[4][2], const float* nRw, const float* nC) {
        const float nc0 = nC[wc * 32 + lrow];
        const float nc1 = nC[wc * 32 + 16 + lrow];
#pragma unroll
        for (int m = 0; m < 4; ++m) {
            float nr[4];
#pragma unroll
            for (int r = 0; r < 4; ++r)
                nr[r] = nRw[wr * 64 + m * 16 + lkb * 4 + r];
#pragma unroll
            for (int nf = 0; nf < 2; ++nf) {
                const float nc = nf ? nc1 : nc0;
#pragma unroll
                for (int r = 0; r < 4; ++r) {
                    float sq = nr[r] + nc - 2.f * acc[m][nf][r];
                    acc[m][nf][r] = __builtin_amdgcn_sqrtf(fmaxf(sq, 0.f));
                }
            }
        }
        if (diag) {   // only 64/2080 blocks
#pragma unroll
            for (int m = 0; m < 4; ++m)
#pragma unroll
                for (int nf = 0; nf < 2; ++nf)
#pragma unroll
                    for (int r = 0; r < 4; ++r) {
                        int row_l = wr * 64 + m * 16 + lkb * 4 + r;
                        int col_l = wc * 32 + nf * 16 + lrow;
                        if (row_l == col_l) acc[m][nf][r] = 0.f;
                    }
        }
    };

    const f32x4 fz = {0.f, 0.f, 0.f, 0.f};
    f32x4 accX[4][2];
#pragma unroll
    for (int m = 0; m < 4; ++m)
#pragma unroll
        for (int nf = 0; nf < 2; ++nf) accX[m][nf] = fz;

    // ---- sched_barrier-fenced 2-deep ping-pong (no barriers) ----
    bf16x8 ca[4], cb[2], na[4], nb[2];
    LOADOPS(ca, cb, TiX, TjX, 0);    SBAR();   // x0 issued
    LOADOPS(na, nb, TiX, TjX, 1);    SBAR();   // x1 issued
    MFMA8(ca, cb, accX);             SBAR();   // x0 (waits with x1 flying)
    LOADOPS(ca, cb, TiX, TjX, 2);    SBAR();   // x2 issued
    MFMA8(na, nb, accX);             SBAR();   // x1
    LOADOPS(na, nb, TiX, TjX, 3);    SBAR();   // x3 issued
    MFMA8(ca, cb, accX);             SBAR();   // x2
    LOADOPS(ca, cb, TiY, TjY, 0);    SBAR();   // y0 issued
    MFMA8(na, nb, accX);             SBAR();   // x3
    LOADOPS(na, nb, TiY, TjY, 1);    SBAR();   // y1 issued

    to_dist(accX, nl[0], nl[1]);               // long VALU covers y0/y1
    unsigned dxb[16];                          // X distances -> bf16 pairs
#pragma unroll
    for (int m = 0; m < 4; ++m)
#pragma unroll
        for (int nf = 0; nf < 2; ++nf)
#pragma unroll
            for (int rp = 0; rp < 2; ++rp) {
                bf16x2 pk;
                pk.x = (__bf16)accX[m][nf][2 * rp];
                pk.y = (__bf16)accX[m][nf][2 * rp + 1];
                dxb[m * 4 + nf * 2 + rp] = __builtin_bit_cast(unsigned, pk);
            }
    f32x4 accY[4][2];                          // init deferred: pressure
#pragma unroll
    for (int m = 0; m < 4; ++m)
#pragma unroll
        for (int nf = 0; nf < 2; ++nf) accY[m][nf] = fz;
    SBAR();
    MFMA8(ca, cb, accY);             SBAR();   // y0
    LOADOPS(ca, cb, TiY, TjY, 2);    SBAR();   // y2 issued
    MFMA8(na, nb, accY);             SBAR();   // y1
    LOADOPS(na, nb, TiY, TjY, 3);    SBAR();   // y3 issued
    MFMA8(ca, cb, accY);             SBAR();   // y2
    MFMA8(na, nb, accY);             SBAR();   // y3
    to_dist(accY, nl[2], nl[3]);               // accY = Y distances

    // ---- combine (R7 form: dxb-packed X) ----
    float pxy = 0.f, pxx = 0.f, pyy = 0.f;
    float ax[16], ay[16];
    float csx[2] = {0.f, 0.f}, csy[2] = {0.f, 0.f};
#pragma unroll
    for (int j = 0; j < 16; ++j) { ax[j] = 0.f; ay[j] = 0.f; }

#pragma unroll
    for (int m = 0; m < 4; ++m)
#pragma unroll
        for (int nf = 0; nf < 2; ++nf)
#pragma unroll
            for (int rp = 0; rp < 2; ++rp) {
                unsigned u = dxb[m * 4 + nf * 2 + rp];
                float dx0 = __builtin_bit_cast(float, u << 16);
                float dx1 = __builtin_bit_cast(float, u & 0xFFFF0000u);
                float dy0 = accY[m][nf][2 * rp], dy1 = accY[m][nf][2 * rp + 1];
                pxy += dx0 * dy0 + dx1 * dy1;
                pxx += dx0 * dx0 + dx1 * dx1;
                pyy += dy0 * dy0 + dy1 * dy1;
                ax[m * 4 + 2 * rp] += dx0; ax[m * 4 + 2 * rp + 1] += dx1;
                ay[m * 4 + 2 * rp] += dy0; ay[m * 4 + 2 * rp + 1] += dy1;
                csx[nf] += dx0 + dx1;      csy[nf] += dy0 + dy1;
            }

    // butterfly: 15 shuffles reduce 16 values over the 16-lane lrow group
    BSTEP(ax, 0) BSTEP(ay, 0)
    BSTEP(ax, 1) BSTEP(ay, 1)
    BSTEP(ax, 2) BSTEP(ay, 2)
    BSTEP(ax, 3) BSTEP(ay, 3)
    {   // j = lrow -> row = (j>>2)*16 + lkb*4 + (j&3); bijective over 64 rows
        int row_l = wr * 64 + ((lrow >> 2) << 4) + (lkb << 2) + (lrow & 3);
        atomicAdd(&rsum[0][row_l], ax[0]);
        atomicAdd(&rsum[1][row_l], ay[0]);
    }
    // col sums: reduce across the 4 lkb groups
#pragma unroll
    for (int nf = 0; nf < 2; ++nf) {
        float vx = csx[nf], vy = csy[nf];
        vx += __shfl_xor(vx, 16); vx += __shfl_xor(vx, 32);
        vy += __shfl_xor(vy, 16); vy += __shfl_xor(vy, 32);
        if (lkb == 0) {
            int col_l = wc * 32 + nf * 16 + lrow;
            atomicAdd(&rsum[2][col_l], vx);
            atomicAdd(&rsum[3][col_l], vy);
        }
    }
    // scalar products: wave reduce -> per-wave slot
#pragma unroll
    for (int m = 1; m < 64; m <<= 1) {
        pxy += __shfl_xor(pxy, m);
        pxx += __shfl_xor(pxx, m);
        pyy += __shfl_xor(pyy, m);
    }
    if (lane == 0) { pr[0][wid] = pxy; pr[1][wid] = pxx; pr[2][wid] = pyy; }
    __syncthreads();                 // B2: epilogue

    if (tid == 0) {
        double sxy = 0, sxx = 0, syy = 0;
#pragma unroll
        for (int w = 0; w < 8; ++w) {
            sxy += (double)pr[0][w]; sxx += (double)pr[1][w]; syy += (double)pr[2][w];
        }
        double sc = diag ? 1.0 : 2.0;
        Pp[t] = sxy * sc;
        Pp[NT + t] = sxx * sc;
        Pp[2 * NT + t] = syy * sc;
    }
    if (tid < TILE) {   // each RP slot written by exactly one block
        RPx[((size_t)bi * GB + bj) * TILE + tid] = rsum[0][tid];
        RPy[((size_t)bi * GB + bj) * TILE + tid] = rsum[1][tid];
        if (!diag) {
            RPx[((size_t)bj * GB + bi) * TILE + tid] = rsum[2][tid];
            RPy[((size_t)bj * GB + bi) * TILE + tid] = rsum[3][tid];
        }
    }
}

// Fold per-tile partials into full row sums AND the 5 row-sum scalars.
__global__ __launch_bounds__(128) void row_reduce2(
    const float* __restrict__ RPx, const float* __restrict__ RPy,
    double* __restrict__ SB /* [GB][5] */)
{
    int b = blockIdx.x, t = threadIdx.x;
    double rx = 0.0, ry = 0.0;
    for (int k = 0; k < GB; ++k) {
        rx += (double)RPx[((size_t)b * GB + k) * TILE + t];
        ry += (double)RPy[((size_t)b * GB + k) * TILE + t];
    }
    double s0 = rx, s1 = ry, s2 = rx * ry, s3 = rx * rx, s4 = ry * ry;
#pragma unroll
    for (int m = 1; m < 64; m <<= 1) {
        s0 += __shfl_xor(s0, m); s1 += __shfl_xor(s1, m);
        s2 += __shfl_xor(s2, m); s3 += __shfl_xor(s3, m);
        s4 += __shfl_xor(s4, m);
    }
    __shared__ double sb[5][2];
    int lane = t & 63, w = t >> 6;
    if (lane == 0) { sb[0][w] = s0; sb[1][w] = s1; sb[2][w] = s2; sb[3][w] = s3; sb[4][w] = s4; }
    __syncthreads();
    if (t == 0)
#pragma unroll
        for (int i = 0; i < 5; ++i) SB[b * 5 + i] = sb[i][0] + sb[i][1];
}

__global__ __launch_bounds__(256) void dcor_final3(
    const double* __restrict__ SB, const double* __restrict__ Pp,
    unsigned* __restrict__ out)
{
    double sx = 0, sy = 0, sxy = 0, sxx = 0, syy = 0, pxy = 0, pxx = 0, pyy = 0;
    for (int b = threadIdx.x; b < GB; b += 256) {
        sx += SB[b * 5]; sy += SB[b * 5 + 1]; sxy += SB[b * 5 + 2];
        sxx += SB[b * 5 + 3]; syy += SB[b * 5 + 4];
    }
    for (int b = threadIdx.x; b < NT; b += 256) {
        pxy += Pp[b]; pxx += Pp[NT + b]; pyy += Pp[2 * NT + b];
    }
    __shared__ double red[8][4];
    int lane = threadIdx.x & 63, w = threadIdx.x >> 6;
#pragma unroll
    for (int m = 1; m < 64; m <<= 1) {
        sx += __shfl_xor(sx, m);  sy += __shfl_xor(sy, m);
        sxy += __shfl_xor(sxy, m); sxx += __shfl_xor(sxx, m); syy += __shfl_xor(syy, m);
        pxy += __shfl_xor(pxy, m); pxx += __shfl_xor(pxx, m); pyy += __shfl_xor(pyy, m);
    }
    if (lane == 0) {
        red[0][w] = sx;  red[1][w] = sy;  red[2][w] = sxy; red[3][w] = sxx;
        red[4][w] = syy; red[5][w] = pxy; red[6][w] = pxx; red[7][w] = pyy;
    }
    __syncthreads();
    if (threadIdx.x == 0) {
        sx  = red[0][0] + red[0][1] + red[0][2] + red[0][3];
        sy  = red[1][0] + red[1][1] + red[1][2] + red[1][3];
        sxy = red[2][0] + red[2][1] + red[2][2] + red[2][3];
        sxx = red[3][0] + red[3][1] + red[3][2] + red[3][3];
        syy = red[4][0] + red[4][1] + red[4][2] + red[4][3];
        pxy = red[5][0] + red[5][1] + red[5][2] + red[5][3];
        pxx = red[6][0] + red[6][1] + red[6][2] + red[6][3];
        pyy = red[7][0] + red[7][1] + red[7][2] + red[7][3];
        const double inv = 1.0 / (double)NR;
        double vxy = pxy - 2.0 * inv * sxy + sx * sy * inv * inv;
        double vxx = pxx - 2.0 * inv * sxx + sx * sx * inv * inv;
        double vyy = pyy - 2.0 * inv * syy + sy * sy * inv * inv;
        vxy = fmax(vxy, 0.0);
        vxx = fmax(vxx, 1e-30); vyy = fmax(vyy, 1e-30);
        double dcor = -sqrt(vxy) / sqrt(sqrt(vxx) * sqrt(vyy));
        unsigned short b = bf16_rne((float)dcor);
        out[0] = ((unsigned)b << 16) | (unsigned)b;   // f32-and-bf16 valid
    }
}

extern "C" void kernel_launch(void* const* d_in, const int* in_sizes, int n_in,
                              void* d_out, int out_size, void* d_ws, size_t ws_size,
                              hipStream_t stream)
{
    const float* x = (const float*)d_in[0];
    const float* y = (const float*)d_in[1];
    char* ws = (char*)d_ws;
    unsigned short* xb = (unsigned short*)(ws);
    unsigned short* yb = (unsigned short*)(ws + OFF_YB);
    float* nx = (float*)(ws + OFF_NX);
    float* ny = (float*)(ws + OFF_NY);
    float* RPx = (float*)(ws + OFF_RPX);
    float* RPy = (float*)(ws + OFF_RPY);
    double* Pp = (double*)(ws + OFF_PP);
    double* SB = (double*)(ws + OFF_SB);

    prep_kernel<<<4096, 256, 0, stream>>>(x, y, xb, yb, nx, ny);
    dcor_main12<<<NT, 512, 0, stream>>>(xb, yb, nx, ny, RPx, RPy, Pp);
    row_reduce2<<<GB, 128, 0, stream>>>(RPx, RPy, SB);
    dcor_final3<<<1, 256, 0, stream>>>(SB, Pp, (unsigned*)d_out);
}

// Round 15
// 94.751 us; speedup vs baseline: 1.5760x; 1.5760x over previous
//
#include <hip/hip_runtime.h>

// DcorLoss: dcor(x, y) for x,y [8192,128] fp32 -> single scalar.
//
// <HaH,HbH> = sum(a_ij b_ij) - (2/n) sum_i ra_i rb_i + Sa Sb/n^2: fused pass
// over pair-tiles: bf16 gram (MFMA 16x16x32) -> distances -> scalar products
// + row/col sums. Upper triangle; off-diag doubled + transposed col-sums.
//
// R15: ZERO-SYNC SINGLE-WAVE BLOCKS. All prior rounds' cost was 8-wave
// barrier convoys (per-block critical path ~18us vs ~3us pipe work).
// global_load_lds is per-wave and s_waitcnt vmcnt is wave-local, so a wave
// that stages only data IT reads needs no s_barrier at all. 64-thread
// blocks, one 64x64 tile per wave (8256 tiles), private 3-buffer LDS ring
// (24KB), counted vmcnt(8) stage-ahead-2 pipeline, XOR sub-chunk swizzle
// (2-way banks = free). Butterfly ends lane<->row bijective -> one global
// f32 atomicAdd per lane (memset-zeroed Rx/Ry); Pp unique per tile.
// 6 independent wave-pipelines per CU; no convoys anywhere.

typedef float f32x4 __attribute__((ext_vector_type(4)));
typedef __bf16 bf16x8 __attribute__((ext_vector_type(8)));
typedef __bf16 bf16x2 __attribute__((ext_vector_type(2)));

#define NR 8192
#define D 128
#define NB 128         /* row blocks of 64 */
#define NT2 8256       /* NB*(NB+1)/2 */

// ---------------- workspace layout (bytes) ----------------
#define OFF_YB  2097152u
#define OFF_NX  4194304u
#define OFF_NY  (OFF_NX + 32768u)
#define OFF_RX  (OFF_NY + 32768u)     /* 8192 f32 (memset 0) */
#define OFF_RY  (OFF_RX + 32768u)     /* 8192 f32 (memset 0) */
#define OFF_PP  (OFF_RY + 32768u)     /* 3*8256 f64 */
#define WS_NEED (OFF_PP + 198144u)

#define GLOAD_LDS16(g, l)                                                  \
    __builtin_amdgcn_global_load_lds(                                      \
        (const __attribute__((address_space(1))) unsigned*)(g),            \
        (__attribute__((address_space(3))) unsigned*)(l), 16, 0, 0)

#define WAITV(N)                                                           \
    do {                                                                   \
        asm volatile("s_waitcnt vmcnt(" #N ")" ::: "memory");              \
        __builtin_amdgcn_sched_barrier(0);                                 \
    } while (0)

__device__ __forceinline__ unsigned short bf16_rne(float f) {
    union { float f; unsigned u; } c; c.f = f;
    unsigned u = c.u;
    u += 0x7FFFu + ((u >> 16) & 1u);
    return (unsigned short)(u >> 16);
}

// One wave per row: fp32 -> bf16 (RNE), linear panels + fp32 row sq-norm.
__global__ __launch_bounds__(256) void prep_kernel(
    const float* __restrict__ x, const float* __restrict__ y,
    unsigned short* __restrict__ xb, unsigned short* __restrict__ yb,
    float* __restrict__ nx, float* __restrict__ ny)
{
    int gid = blockIdx.x * 256 + threadIdx.x;
    int wave = gid >> 6;
    int lane = threadIdx.x & 63;
    const float* src; unsigned short* db; float* dn; int row;
    if (wave < NR) { src = x; db = xb; dn = nx; row = wave; }
    else           { src = y; db = yb; dn = ny; row = wave - NR; }

    const float2 v = *reinterpret_cast<const float2*>(src + (size_t)row * D + lane * 2);
    float s = v.x * v.x + v.y * v.y;
    unsigned packed = (unsigned)bf16_rne(v.x) | ((unsigned)bf16_rne(v.y) << 16);
    *reinterpret_cast<unsigned*>(db + (size_t)row * D + lane * 2) = packed;
#pragma unroll
    for (int m = 1; m < 64; m <<= 1) s += __shfl_xor(s, m);
    if (lane == 0) dn[row] = s;
}

// butterfly step S for a 16-value array reduced over the 16-lane lrow group
#define BSTEP(arr, S) {                                                    \
    const int b_ = (lrow >> (S)) & 1;                                      \
    _Pragma("unroll")                                                      \
    for (int i_ = 0; i_ < (8 >> (S)); ++i_) {                              \
        float k_ = b_ ? arr[2 * i_ + 1] : arr[2 * i_];                     \
        float s_ = b_ ? arr[2 * i_] : arr[2 * i_ + 1];                     \
        arr[i_] = k_ + __shfl_xor(s_, 1 << (S));                           \
    } }

// One 64x64 pair-tile per 64-thread block (one wave). 4x4 frags of
// mfma_f32_16x16x32_bf16, K=128 in 4 chunks of 32, 3-buffer wave-private
// ring, counted vmcnt, NO barriers anywhere.
__global__ __launch_bounds__(64) void dcor_wave(
    const unsigned short* __restrict__ xb, const unsigned short* __restrict__ yb,
    const float* __restrict__ nx, const float* __restrict__ ny,
    float* __restrict__ Rx, float* __restrict__ Ry,
    double* __restrict__ Pp /* [3][NT2] */)
{
    // XCD-chunked swizzle (NT2 % 8 == 0 -> bijective)
    const int t = (blockIdx.x & 7) * (NT2 / 8) + (blockIdx.x >> 3);
    // triangular decode t -> (bi, bj), bi <= bj over NB=128
    double qd = 2.0 * NB + 1.0;
    int bi = (int)((qd - sqrt(qd * qd - 8.0 * (double)t)) * 0.5);
    while (bi > 0 && bi * NB - bi * (bi - 1) / 2 > t) --bi;
    while ((bi + 1) * NB - (bi + 1) * bi / 2 <= t) ++bi;
    const int bj = bi + (t - (bi * NB - bi * (bi - 1) / 2));
    const bool diag = (bi == bj);

    // [ring][A/B][64 rows][32 bf16]; sub-chunk slot s = q ^ ((row>>1)&3)
    __shared__ __align__(16) unsigned short Buf[3][2][64][32];
    __shared__ float nlds[4][64];   // 0:x rows(bi) 1:x cols(bj) 2:y 3:y

    const int lane = threadIdx.x;            // 0..63, one wave
    const int lrow = lane & 15, lkb = lane >> 4;

    // norms -> LDS (wave-local; compiler's own waitcnts order this)
    nlds[0][lane] = nx[bi * 64 + lane];
    nlds[1][lane] = nx[bj * 64 + lane];
    nlds[2][lane] = ny[bi * 64 + lane];
    nlds[3][lane] = ny[bj * 64 + lane];
    __builtin_amdgcn_sched_barrier(0);       // pin: before pipeline starts

    // stage chunk kc of both tiles into ring buffer b: 8 x 1KB gload_lds
    auto stagec = [&](int b, const unsigned short* srcb, int kc) {
        const char* gb = (const char*)srcb;
#pragma unroll
        for (int w = 0; w < 2; ++w) {
            int blk = w ? bj : bi;
#pragma unroll
            for (int seg = 0; seg < 4; ++seg) {
                int r = seg * 16 + (lane >> 2);
                int c = (lane & 3) ^ ((r >> 1) & 3);     // logical sub-chunk
                const char* g = gb + (size_t)(blk * 64 + r) * 256 + kc * 64 + c * 16;
                GLOAD_LDS16(g, &Buf[b][w][seg * 16][0]);
            }
        }
    };

    // swizzled read offset: uniform across m since (m*16)>>1 ≡ 0 (mod 4)
    const int sA = (lkb ^ ((lrow >> 1) & 3)) << 4;

    auto gram = [&](int b, f32x4 (&acc)[4][4]) {
        const char* A = (const char*)&Buf[b][0][0][0];
        const char* B = (const char*)&Buf[b][1][0][0];
        bf16x8 av[4], bv[4];
#pragma unroll
        for (int m = 0; m < 4; ++m)
            av[m] = *reinterpret_cast<const bf16x8*>(A + (m * 16 + lrow) * 64 + sA);
#pragma unroll
        for (int nf = 0; nf < 4; ++nf)
            bv[nf] = *reinterpret_cast<const bf16x8*>(B + (nf * 16 + lrow) * 64 + sA);
#pragma unroll
        for (int m = 0; m < 4; ++m)
#pragma unroll
            for (int nf = 0; nf < 4; ++nf)
                acc[m][nf] = __builtin_amdgcn_mfma_f32_16x16x32_bf16(
                    av[m], bv[nf], acc[m][nf], 0, 0, 0);
    };

    // C frag: row=(lane>>4)*4+r, col=lane&15. Raw v_sqrt; LDS norms.
    auto to_dist = [&](f32x4 (&acc)[4][4], int selR, int selC) {
        float nc[4];
#pragma unroll
        for (int nf = 0; nf < 4; ++nf) nc[nf] = nlds[selC][nf * 16 + lrow];
#pragma unroll
        for (int m = 0; m < 4; ++m) {
            const f32x4 nr4 = *reinterpret_cast<const f32x4*>(
                &nlds[selR][m * 16 + lkb * 4]);
#pragma unroll
            for (int nf = 0; nf < 4; ++nf)
#pragma unroll
                for (int r = 0; r < 4; ++r) {
                    float sq = nr4[r] + nc[nf] - 2.f * acc[m][nf][r];
                    acc[m][nf][r] = __builtin_amdgcn_sqrtf(fmaxf(sq, 0.f));
                }
        }
        if (diag) {
#pragma unroll
            for (int m = 0; m < 4; ++m)
#pragma unroll
                for (int nf = 0; nf < 4; ++nf)
#pragma unroll
                    for (int r = 0; r < 4; ++r) {
                        int row_l = m * 16 + lkb * 4 + r;
                        int col_l = nf * 16 + lrow;
                        if (row_l == col_l) acc[m][nf][r] = 0.f;
                    }
        }
    };

    const f32x4 fz = {0.f, 0.f, 0.f, 0.f};
    f32x4 accX[4][4];
#pragma unroll
    for (int m = 0; m < 4; ++m)
#pragma unroll
        for (int nf = 0; nf < 4; ++nf) accX[m][nf] = fz;

    // ---- wave-private pipeline: chunks c0..c7 = x0-3,y0-3; buf = c%3 ----
    stagec(0, xb, 0); stagec(1, xb, 1);      // vm 16
    WAITV(8);  stagec(2, xb, 2); gram(0, accX);       // P0 (c0)
    WAITV(8);  stagec(0, xb, 3); gram(1, accX);       // P1 (c1)
    WAITV(8);  stagec(1, yb, 0); gram(2, accX);       // P2 (c2)
    WAITV(8);  stagec(2, yb, 1); gram(0, accX);       // P3 (c3) accX done
    // X distances -> packed bf16 while y0/y1 fly
    to_dist(accX, 0, 1);
    unsigned dxb[32];
#pragma unroll
    for (int m = 0; m < 4; ++m)
#pragma unroll
        for (int nf = 0; nf < 4; ++nf)
#pragma unroll
            for (int rp = 0; rp < 2; ++rp) {
                bf16x2 pk;
                pk.x = (__bf16)accX[m][nf][2 * rp];
                pk.y = (__bf16)accX[m][nf][2 * rp + 1];
                dxb[(m * 4 + nf) * 2 + rp] = __builtin_bit_cast(unsigned, pk);
            }
    f32x4 accY[4][4];
#pragma unroll
    for (int m = 0; m < 4; ++m)
#pragma unroll
        for (int nf = 0; nf < 4; ++nf) accY[m][nf] = fz;
    WAITV(8);  stagec(0, yb, 2); gram(1, accY);       // P4 (c4=y0)
    WAITV(8);  stagec(1, yb, 3); gram(2, accY);       // P5 (c5=y1)
    WAITV(8);  gram(0, accY);                          // P6 (c6=y2)
    WAITV(0);  gram(1, accY);                          // P7 (c7=y3)
    to_dist(accY, 2, 3);

    // ---- combine ----
    float pxy = 0.f, pxx = 0.f, pyy = 0.f;
    float ax[16], ay[16], csx[4], csy[4];
#pragma unroll
    for (int j = 0; j < 16; ++j) { ax[j] = 0.f; ay[j] = 0.f; }
#pragma unroll
    for (int j = 0; j < 4; ++j) { csx[j] = 0.f; csy[j] = 0.f; }

#pragma unroll
    for (int m = 0; m < 4; ++m)
#pragma unroll
        for (int nf = 0; nf < 4; ++nf)
#pragma unroll
            for (int rp = 0; rp < 2; ++rp) {
                unsigned u = dxb[(m * 4 + nf) * 2 + rp];
                float dx0 = __builtin_bit_cast(float, u << 16);
                float dx1 = __builtin_bit_cast(float, u & 0xFFFF0000u);
                float dy0 = accY[m][nf][2 * rp], dy1 = accY[m][nf][2 * rp + 1];
                pxy += dx0 * dy0 + dx1 * dy1;
                pxx += dx0 * dx0 + dx1 * dx1;
                pyy += dy0 * dy0 + dy1 * dy1;
                ax[m * 4 + 2 * rp] += dx0; ax[m * 4 + 2 * rp + 1] += dx1;
                ay[m * 4 + 2 * rp] += dy0; ay[m * 4 + 2 * rp + 1] += dy1;
                csx[nf] += dx0 + dx1;      csy[nf] += dy0 + dy1;
            }

    // butterfly over 16-lane groups: lane j=lrow owns (m=j>>2, r=j&3);
    // row = (j>>2)*16 + lkb*4 + (j&3) -> 64 lanes <-> 64 rows bijective.
    BSTEP(ax, 0) BSTEP(ay, 0)
    BSTEP(ax, 1) BSTEP(ay, 1)
    BSTEP(ax, 2) BSTEP(ay, 2)
    BSTEP(ax, 3) BSTEP(ay, 3)
    {
        int row_l = ((lrow >> 2) << 4) + (lkb << 2) + (lrow & 3);
        atomicAdd(&Rx[bi * 64 + row_l], ax[0]);
        atomicAdd(&Ry[bi * 64 + row_l], ay[0]);
    }
    // col sums across lkb groups -> transposed rows (off-diag only)
#pragma unroll
    for (int nf = 0; nf < 4; ++nf) {
        float vx = csx[nf], vy = csy[nf];
        vx += __shfl_xor(vx, 16); vx += __shfl_xor(vx, 32);
        vy += __shfl_xor(vy, 16); vy += __shfl_xor(vy, 32);
        if (lkb == 0 && !diag) {
            atomicAdd(&Rx[bj * 64 + nf * 16 + lrow], vx);
            atomicAdd(&Ry[bj * 64 + nf * 16 + lrow], vy);
        }
    }
    // scalar products: full-wave reduce, lane 0 writes unique Pp slot
#pragma unroll
    for (int m = 1; m < 64; m <<= 1) {
        pxy += __shfl_xor(pxy, m);
        pxx += __shfl_xor(pxx, m);
        pyy += __shfl_xor(pyy, m);
    }
    if (lane == 0) {
        double sc = diag ? 1.0 : 2.0;
        Pp[t] = (double)pxy * sc;
        Pp[NT2 + t] = (double)pxx * sc;
        Pp[2 * NT2 + t] = (double)pyy * sc;
    }
}

__global__ __launch_bounds__(256) void dcor_final4(
    const float* __restrict__ Rx, const float* __restrict__ Ry,
    const double* __restrict__ Pp, unsigned* __restrict__ out)
{
    double sx = 0, sy = 0, sxy = 0, sxx = 0, syy = 0, pxy = 0, pxx = 0, pyy = 0;
    for (int i = threadIdx.x; i < NR; i += 256) {
        double rx = (double)Rx[i], ry = (double)Ry[i];
        sx += rx; sy += ry; sxy += rx * ry; sxx += rx * rx; syy += ry * ry;
    }
    for (int b = threadIdx.x; b < NT2; b += 256) {
        pxy += Pp[b]; pxx += Pp[NT2 + b]; pyy += Pp[2 * NT2 + b];
    }
    __shared__ double red[8][4];
    int lane = threadIdx.x & 63, w = threadIdx.x >> 6;
#pragma unroll
    for (int m = 1; m < 64; m <<= 1) {
        sx += __shfl_xor(sx, m);  sy += __shfl_xor(sy, m);
        sxy += __shfl_xor(sxy, m); sxx += __shfl_xor(sxx, m); syy += __shfl_xor(syy, m);
        pxy += __shfl_xor(pxy, m); pxx += __shfl_xor(pxx, m); pyy += __shfl_xor(pyy, m);
    }
    if (lane == 0) {
        red[0][w] = sx;  red[1][w] = sy;  red[2][w] = sxy; red[3][w] = sxx;
        red[4][w] = syy; red[5][w] = pxy; red[6][w] = pxx; red[7][w] = pyy;
    }
    __syncthreads();
    if (threadIdx.x == 0) {
        sx  = red[0][0] + red[0][1] + red[0][2] + red[0][3];
        sy  = red[1][0] + red[1][1] + red[1][2] + red[1][3];
        sxy = red[2][0] + red[2][1] + red[2][2] + red[2][3];
        sxx = red[3][0] + red[3][1] + red[3][2] + red[3][3];
        syy = red[4][0] + red[4][1] + red[4][2] + red[4][3];
        pxy = red[5][0] + red[5][1] + red[5][2] + red[5][3];
        pxx = red[6][0] + red[6][1] + red[6][2] + red[6][3];
        pyy = red[7][0] + red[7][1] + red[7][2] + red[7][3];
        const double inv = 1.0 / (double)NR;
        double vxy = pxy - 2.0 * inv * sxy + sx * sy * inv * inv;
        double vxx = pxx - 2.0 * inv * sxx + sx * sx * inv * inv;
        double vyy = pyy - 2.0 * inv * syy + sy * sy * inv * inv;
        vxy = fmax(vxy, 0.0);
        vxx = fmax(vxx, 1e-30); vyy = fmax(vyy, 1e-30);
        double dcor = -sqrt(vxy) / sqrt(sqrt(vxx) * sqrt(vyy));
        unsigned short b = bf16_rne((float)dcor);
        out[0] = ((unsigned)b << 16) | (unsigned)b;   // f32-and-bf16 valid
    }
}

extern "C" void kernel_launch(void* const* d_in, const int* in_sizes, int n_in,
                              void* d_out, int out_size, void* d_ws, size_t ws_size,
                              hipStream_t stream)
{
    const float* x = (const float*)d_in[0];
    const float* y = (const float*)d_in[1];
    char* ws = (char*)d_ws;
    unsigned short* xb = (unsigned short*)(ws);
    unsigned short* yb = (unsigned short*)(ws + OFF_YB);
    float* nx = (float*)(ws + OFF_NX);
    float* ny = (float*)(ws + OFF_NY);
    float* Rx = (float*)(ws + OFF_RX);
    float* Ry = (float*)(ws + OFF_RY);
    double* Pp = (double*)(ws + OFF_PP);

    prep_kernel<<<4096, 256, 0, stream>>>(x, y, xb, yb, nx, ny);
    hipMemsetAsync(ws + OFF_RX, 0, 65536, stream);   // zero Rx, Ry
    dcor_wave<<<NT2, 64, 0, stream>>>(xb, yb, nx, ny, Rx, Ry, Pp);
    dcor_final4<<<1, 256, 0, stream>>>(Rx, Ry, Pp, (unsigned*)d_out);
}

// Round 16
// 94.109 us; speedup vs baseline: 1.5868x; 1.0068x over previous
//
#include <hip/hip_runtime.h>

// DcorLoss: dcor(x, y) for x,y [8192,128] fp32 -> single scalar.
//
// <HaH,HbH> = sum(a_ij b_ij) - (2/n) sum_i ra_i rb_i + Sa Sb/n^2: fused pass
// over pair-tiles: bf16 gram (MFMA 16x16x32) -> distances -> scalar products
// + row/col sums. Upper triangle; off-diag doubled + transposed col-sums.
//
// R16: R15's zero-sync single-wave blocks (64-thr, one 64x64 tile/wave,
// counted wave-local vmcnt, no s_barrier) with RING-2 staging: 16KB buffers
// + 1KB norms = 17KB LDS -> 9 blocks/CU (was 6 at 25.6KB). Stage-ahead-1:
// restage of a buffer issues after the MFMAs that read it (in-order wave
// issue + compiler lgkm waits) -- race-free; vmcnt(8) retires the current
// chunk with the next in flight. Rx/Ry zeroing folded into prep (no
// separate memset dispatch). Everything else identical to R15.

typedef float f32x4 __attribute__((ext_vector_type(4)));
typedef __bf16 bf16x8 __attribute__((ext_vector_type(8)));
typedef __bf16 bf16x2 __attribute__((ext_vector_type(2)));

#define NR 8192
#define D 128
#define NB 128         /* row blocks of 64 */
#define NT2 8256       /* NB*(NB+1)/2 */

// ---------------- workspace layout (bytes) ----------------
#define OFF_YB  2097152u
#define OFF_NX  4194304u
#define OFF_NY  (OFF_NX + 32768u)
#define OFF_RX  (OFF_NY + 32768u)     /* 8192 f32 (zeroed by prep) */
#define OFF_RY  (OFF_RX + 32768u)     /* 8192 f32 (zeroed by prep) */
#define OFF_PP  (OFF_RY + 32768u)     /* 3*8256 f64 */
#define WS_NEED (OFF_PP + 198144u)

#define GLOAD_LDS16(g, l)                                                  \
    __builtin_amdgcn_global_load_lds(                                      \
        (const __attribute__((address_space(1))) unsigned*)(g),            \
        (__attribute__((address_space(3))) unsigned*)(l), 16, 0, 0)

#define WAITV(N)                                                           \
    do {                                                                   \
        asm volatile("s_waitcnt vmcnt(" #N ")" ::: "memory");              \
        __builtin_amdgcn_sched_barrier(0);                                 \
    } while (0)

__device__ __forceinline__ unsigned short bf16_rne(float f) {
    union { float f; unsigned u; } c; c.f = f;
    unsigned u = c.u;
    u += 0x7FFFu + ((u >> 16) & 1u);
    return (unsigned short)(u >> 16);
}

// One wave per row: fp32 -> bf16 (RNE), linear panels + fp32 row sq-norm.
// First 16384 threads also zero Rx/Ry (accumulators for dcor_wave).
__global__ __launch_bounds__(256) void prep_kernel(
    const float* __restrict__ x, const float* __restrict__ y,
    unsigned short* __restrict__ xb, unsigned short* __restrict__ yb,
    float* __restrict__ nx, float* __restrict__ ny,
    float* __restrict__ Rz /* Rx followed by Ry: 16384 f32 */)
{
    int gid = blockIdx.x * 256 + threadIdx.x;
    if (gid < 2 * NR) Rz[gid] = 0.f;
    int wave = gid >> 6;
    int lane = threadIdx.x & 63;
    const float* src; unsigned short* db; float* dn; int row;
    if (wave < NR) { src = x; db = xb; dn = nx; row = wave; }
    else           { src = y; db = yb; dn = ny; row = wave - NR; }

    const float2 v = *reinterpret_cast<const float2*>(src + (size_t)row * D + lane * 2);
    float s = v.x * v.x + v.y * v.y;
    unsigned packed = (unsigned)bf16_rne(v.x) | ((unsigned)bf16_rne(v.y) << 16);
    *reinterpret_cast<unsigned*>(db + (size_t)row * D + lane * 2) = packed;
#pragma unroll
    for (int m = 1; m < 64; m <<= 1) s += __shfl_xor(s, m);
    if (lane == 0) dn[row] = s;
}

// butterfly step S for a 16-value array reduced over the 16-lane lrow group
#define BSTEP(arr, S) {                                                    \
    const int b_ = (lrow >> (S)) & 1;                                      \
    _Pragma("unroll")                                                      \
    for (int i_ = 0; i_ < (8 >> (S)); ++i_) {                              \
        float k_ = b_ ? arr[2 * i_ + 1] : arr[2 * i_];                     \
        float s_ = b_ ? arr[2 * i_] : arr[2 * i_ + 1];                     \
        arr[i_] = k_ + __shfl_xor(s_, 1 << (S));                           \
    } }

// One 64x64 pair-tile per 64-thread block (one wave). 4x4 frags of
// mfma_f32_16x16x32_bf16, K=128 in 4 chunks of 32, ring-2 wave-private
// staging, counted vmcnt, NO barriers anywhere.
__global__ __launch_bounds__(64) void dcor_wave(
    const unsigned short* __restrict__ xb, const unsigned short* __restrict__ yb,
    const float* __restrict__ nx, const float* __restrict__ ny,
    float* __restrict__ Rx, float* __restrict__ Ry,
    double* __restrict__ Pp /* [3][NT2] */)
{
    // XCD-chunked swizzle (NT2 % 8 == 0 -> bijective)
    const int t = (blockIdx.x & 7) * (NT2 / 8) + (blockIdx.x >> 3);
    // triangular decode t -> (bi, bj), bi <= bj over NB=128
    double qd = 2.0 * NB + 1.0;
    int bi = (int)((qd - sqrt(qd * qd - 8.0 * (double)t)) * 0.5);
    while (bi > 0 && bi * NB - bi * (bi - 1) / 2 > t) --bi;
    while ((bi + 1) * NB - (bi + 1) * bi / 2 <= t) ++bi;
    const int bj = bi + (t - (bi * NB - bi * (bi - 1) / 2));
    const bool diag = (bi == bj);

    // [ring2][A/B][64 rows][32 bf16]; sub-chunk slot s = q ^ ((row>>1)&3)
    __shared__ __align__(16) unsigned short Buf[2][2][64][32];
    __shared__ float nlds[4][64];   // 0:x rows(bi) 1:x cols(bj) 2:y 3:y

    const int lane = threadIdx.x;            // 0..63, one wave
    const int lrow = lane & 15, lkb = lane >> 4;

    // norms -> LDS (wave-local; compiler's own waitcnts order this)
    nlds[0][lane] = nx[bi * 64 + lane];
    nlds[1][lane] = nx[bj * 64 + lane];
    nlds[2][lane] = ny[bi * 64 + lane];
    nlds[3][lane] = ny[bj * 64 + lane];
    __builtin_amdgcn_sched_barrier(0);       // pin: before pipeline starts

    // stage chunk kc of both tiles into ring buffer b: 8 x 1KB gload_lds
    auto stagec = [&](int b, const unsigned short* srcb, int kc) {
        const char* gb = (const char*)srcb;
#pragma unroll
        for (int w = 0; w < 2; ++w) {
            int blk = w ? bj : bi;
#pragma unroll
            for (int seg = 0; seg < 4; ++seg) {
                int r = seg * 16 + (lane >> 2);
                int c = (lane & 3) ^ ((r >> 1) & 3);     // logical sub-chunk
                const char* g = gb + (size_t)(blk * 64 + r) * 256 + kc * 64 + c * 16;
                GLOAD_LDS16(g, &Buf[b][w][seg * 16][0]);
            }
        }
    };

    // swizzled read offset: uniform across m since (m*16)>>1 ≡ 0 (mod 4)
    const int sA = (lkb ^ ((lrow >> 1) & 3)) << 4;

    auto gram = [&](int b, f32x4 (&acc)[4][4]) {
        const char* A = (const char*)&Buf[b][0][0][0];
        const char* B = (const char*)&Buf[b][1][0][0];
        bf16x8 av[4], bv[4];
#pragma unroll
        for (int m = 0; m < 4; ++m)
            av[m] = *reinterpret_cast<const bf16x8*>(A + (m * 16 + lrow) * 64 + sA);
#pragma unroll
        for (int nf = 0; nf < 4; ++nf)
            bv[nf] = *reinterpret_cast<const bf16x8*>(B + (nf * 16 + lrow) * 64 + sA);
#pragma unroll
        for (int m = 0; m < 4; ++m)
#pragma unroll
            for (int nf = 0; nf < 4; ++nf)
                acc[m][nf] = __builtin_amdgcn_mfma_f32_16x16x32_bf16(
                    av[m], bv[nf], acc[m][nf], 0, 0, 0);
    };

    // C frag: row=(lane>>4)*4+r, col=lane&15. Raw v_sqrt; LDS norms.
    auto to_dist = [&](f32x4 (&acc)[4][4], int selR, int selC) {
        float nc[4];
#pragma unroll
        for (int nf = 0; nf < 4; ++nf) nc[nf] = nlds[selC][nf * 16 + lrow];
#pragma unroll
        for (int m = 0; m < 4; ++m) {
            const f32x4 nr4 = *reinterpret_cast<const f32x4*>(
                &nlds[selR][m * 16 + lkb * 4]);
#pragma unroll
            for (int nf = 0; nf < 4; ++nf)
#pragma unroll
                for (int r = 0; r < 4; ++r) {
                    float sq = nr4[r] + nc[nf] - 2.f * acc[m][nf][r];
                    acc[m][nf][r] = __builtin_amdgcn_sqrtf(fmaxf(sq, 0.f));
                }
        }
        if (diag) {
#pragma unroll
            for (int m = 0; m < 4; ++m)
#pragma unroll
                for (int nf = 0; nf < 4; ++nf)
#pragma unroll
                    for (int r = 0; r < 4; ++r) {
                        int row_l = m * 16 + lkb * 4 + r;
                        int col_l = nf * 16 + lrow;
                        if (row_l == col_l) acc[m][nf][r] = 0.f;
                    }
        }
    };

    const f32x4 fz = {0.f, 0.f, 0.f, 0.f};
    f32x4 accX[4][4];
#pragma unroll
    for (int m = 0; m < 4; ++m)
#pragma unroll
        for (int nf = 0; nf < 4; ++nf) accX[m][nf] = fz;

    // ---- ring-2 wave-private pipeline: c0..c7 = x0-3,y0-3; buf = c&1 ----
    // Restage of buf b at phase k+1 is safe: phase k's ds_reads completed
    // (lgkm wait precedes its MFMAs, which precede the restage in issue
    // order); DMA writes land strictly later.
    stagec(0, xb, 0);                                    // vm 8
    stagec(1, xb, 1); WAITV(8); gram(0, accX);           // P0 (c0)
    stagec(0, xb, 2); WAITV(8); gram(1, accX);           // P1 (c1)
    stagec(1, xb, 3); WAITV(8); gram(0, accX);           // P2 (c2)
    stagec(0, yb, 0); WAITV(8); gram(1, accX);           // P3 (c3) accX done
    // X distances -> packed bf16 while y0 flies
    to_dist(accX, 0, 1);
    unsigned dxb[32];
#pragma unroll
    for (int m = 0; m < 4; ++m)
#pragma unroll
        for (int nf = 0; nf < 4; ++nf)
#pragma unroll
            for (int rp = 0; rp < 2; ++rp) {
                bf16x2 pk;
                pk.x = (__bf16)accX[m][nf][2 * rp];
                pk.y = (__bf16)accX[m][nf][2 * rp + 1];
                dxb[(m * 4 + nf) * 2 + rp] = __builtin_bit_cast(unsigned, pk);
            }
    f32x4 accY[4][4];
#pragma unroll
    for (int m = 0; m < 4; ++m)
#pragma unroll
        for (int nf = 0; nf < 4; ++nf) accY[m][nf] = fz;
    stagec(1, yb, 1); WAITV(8); gram(0, accY);           // P4 (c4=y0)
    stagec(0, yb, 2); WAITV(8); gram(1, accY);           // P5 (c5=y1)
    stagec(1, yb, 3); WAITV(8); gram(0, accY);           // P6 (c6=y2)
    WAITV(0); gram(1, accY);                             // P7 (c7=y3)
    to_dist(accY, 2, 3);

    // ---- combine ----
    float pxy = 0.f, pxx = 0.f, pyy = 0.f;
    float ax[16], ay[16], csx[4], csy[4];
#pragma unroll
    for (int j = 0; j < 16; ++j) { ax[j] = 0.f; ay[j] = 0.f; }
#pragma unroll
    for (int j = 0; j < 4; ++j) { csx[j] = 0.f; csy[j] = 0.f; }

#pragma unroll
    for (int m = 0; m < 4; ++m)
#pragma unroll
        for (int nf = 0; nf < 4; ++nf)
#pragma unroll
            for (int rp = 0; rp < 2; ++rp) {
                unsigned u = dxb[(m * 4 + nf) * 2 + rp];
                float dx0 = __builtin_bit_cast(float, u << 16);
                float dx1 = __builtin_bit_cast(float, u & 0xFFFF0000u);
                float dy0 = accY[m][nf][2 * rp], dy1 = accY[m][nf][2 * rp + 1];
                pxy += dx0 * dy0 + dx1 * dy1;
                pxx += dx0 * dx0 + dx1 * dx1;
                pyy += dy0 * dy0 + dy1 * dy1;
                ax[m * 4 + 2 * rp] += dx0; ax[m * 4 + 2 * rp + 1] += dx1;
                ay[m * 4 + 2 * rp] += dy0; ay[m * 4 + 2 * rp + 1] += dy1;
                csx[nf] += dx0 + dx1;      csy[nf] += dy0 + dy1;
            }

    // butterfly over 16-lane groups: lane j=lrow owns (m=j>>2, r=j&3);
    // row = (j>>2)*16 + lkb*4 + (j&3) -> 64 lanes <-> 64 rows bijective.
    BSTEP(ax, 0) BSTEP(ay, 0)
    BSTEP(ax, 1) BSTEP(ay, 1)
    BSTEP(ax, 2) BSTEP(ay, 2)
    BSTEP(ax, 3) BSTEP(ay, 3)
    {
        int row_l = ((lrow >> 2) << 4) + (lkb << 2) + (lrow & 3);
        atomicAdd(&Rx[bi * 64 + row_l], ax[0]);
        atomicAdd(&Ry[bi * 64 + row_l], ay[0]);
    }
    // col sums across lkb groups -> transposed rows (off-diag only)
#pragma unroll
    for (int nf = 0; nf < 4; ++nf) {
        float vx = csx[nf], vy = csy[nf];
        vx += __shfl_xor(vx, 16); vx += __shfl_xor(vx, 32);
        vy += __shfl_xor(vy, 16); vy += __shfl_xor(vy, 32);
        if (lkb == 0 && !diag) {
            atomicAdd(&Rx[bj * 64 + nf * 16 + lrow], vx);
            atomicAdd(&Ry[bj * 64 + nf * 16 + lrow], vy);
        }
    }
    // scalar products: full-wave reduce, lane 0 writes unique Pp slot
#pragma unroll
    for (int m = 1; m < 64; m <<= 1) {
        pxy += __shfl_xor(pxy, m);
        pxx += __shfl_xor(pxx, m);
        pyy += __shfl_xor(pyy, m);
    }
    if (lane == 0) {
        double sc = diag ? 1.0 : 2.0;
        Pp[t] = (double)pxy * sc;
        Pp[NT2 + t] = (double)pxx * sc;
        Pp[2 * NT2 + t] = (double)pyy * sc;
    }
}

__global__ __launch_bounds__(256) void dcor_final4(
    const float* __restrict__ Rx, const float* __restrict__ Ry,
    const double* __restrict__ Pp, unsigned* __restrict__ out)
{
    double sx = 0, sy = 0, sxy = 0, sxx = 0, syy = 0, pxy = 0, pxx = 0, pyy = 0;
    for (int i = threadIdx.x; i < NR; i += 256) {
        double rx = (double)Rx[i], ry = (double)Ry[i];
        sx += rx; sy += ry; sxy += rx * ry; sxx += rx * rx; syy += ry * ry;
    }
    for (int b = threadIdx.x; b < NT2; b += 256) {
        pxy += Pp[b]; pxx += Pp[NT2 + b]; pyy += Pp[2 * NT2 + b];
    }
    __shared__ double red[8][4];
    int lane = threadIdx.x & 63, w = threadIdx.x >> 6;
#pragma unroll
    for (int m = 1; m < 64; m <<= 1) {
        sx += __shfl_xor(sx, m);  sy += __shfl_xor(sy, m);
        sxy += __shfl_xor(sxy, m); sxx += __shfl_xor(sxx, m); syy += __shfl_xor(syy, m);
        pxy += __shfl_xor(pxy, m); pxx += __shfl_xor(pxx, m); pyy += __shfl_xor(pyy, m);
    }
    if (lane == 0) {
        red[0][w] = sx;  red[1][w] = sy;  red[2][w] = sxy; red[3][w] = sxx;
        red[4][w] = syy; red[5][w] = pxy; red[6][w] = pxx; red[7][w] = pyy;
    }
    __syncthreads();
    if (threadIdx.x == 0) {
        sx  = red[0][0] + red[0][1] + red[0][2] + red[0][3];
        sy  = red[1][0] + red[1][1] + red[1][2] + red[1][3];
        sxy = red[2][0] + red[2][1] + red[2][2] + red[2][3];
        sxx = red[3][0] + red[3][1] + red[3][2] + red[3][3];
        syy = red[4][0] + red[4][1] + red[4][2] + red[4][3];
        pxy = red[5][0] + red[5][1] + red[5][2] + red[5][3];
        pxx = red[6][0] + red[6][1] + red[6][2] + red[6][3];
        pyy = red[7][0] + red[7][1] + red[7][2] + red[7][3];
        const double inv = 1.0 / (double)NR;
        double vxy = pxy - 2.0 * inv * sxy + sx * sy * inv * inv;
        double vxx = pxx - 2.0 * inv * sxx + sx * sx * inv * inv;
        double vyy = pyy - 2.0 * inv * syy + sy * sy * inv * inv;
        vxy = fmax(vxy, 0.0);
        vxx = fmax(vxx, 1e-30); vyy = fmax(vyy, 1e-30);
        double dcor = -sqrt(vxy) / sqrt(sqrt(vxx) * sqrt(vyy));
        unsigned short b = bf16_rne((float)dcor);
        out[0] = ((unsigned)b << 16) | (unsigned)b;   // f32-and-bf16 valid
    }
}

extern "C" void kernel_launch(void* const* d_in, const int* in_sizes, int n_in,
                              void* d_out, int out_size, void* d_ws, size_t ws_size,
                              hipStream_t stream)
{
    const float* x = (const float*)d_in[0];
    const float* y = (const float*)d_in[1];
    char* ws = (char*)d_ws;
    unsigned short* xb = (unsigned short*)(ws);
    unsigned short* yb = (unsigned short*)(ws + OFF_YB);
    float* nx = (float*)(ws + OFF_NX);
    float* ny = (float*)(ws + OFF_NY);
    float* Rx = (float*)(ws + OFF_RX);
    float* Ry = (float*)(ws + OFF_RY);
    double* Pp = (double*)(ws + OFF_PP);

    prep_kernel<<<4096, 256, 0, stream>>>(x, y, xb, yb, nx, ny, Rx);
    dcor_wave<<<NT2, 64, 0, stream>>>(xb, yb, nx, ny, Rx, Ry, Pp);
    dcor_final4<<<1, 256, 0, stream>>>(Rx, Ry, Pp, (unsigned*)d_out);
}